// Round 5
// baseline (725.171 us; speedup 1.0000x reference)
//
#include <hip/hip_runtime.h>
#include <hip/hip_bf16.h>
#include <math.h>

// ---------------- types / helpers ----------------
typedef float f32x4 __attribute__((ext_vector_type(4)));
typedef short s16x8 __attribute__((ext_vector_type(8)));
typedef unsigned short us;

__device__ __forceinline__ float bf2f(us u){
  union { unsigned int i; float f; } v; v.i = ((unsigned int)u) << 16; return v.f;
}
__device__ __forceinline__ us f2bf(float f){
  union { float f; unsigned int i; } v; v.f = f;
  unsigned int r = v.i + 0x7FFFu + ((v.i >> 16) & 1u);
  return (us)(r >> 16);
}
__device__ __forceinline__ float dot4(f32x4 a, f32x4 b){
  return a.x*b.x + a.y*b.y + a.z*b.z + a.w*b.w;
}
__device__ __forceinline__ f32x4 mfma16(s16x8 a, s16x8 b, f32x4 c){
  return __builtin_amdgcn_mfma_f32_16x16x32_bf16(a, b, c, 0, 0, 0);
}
// async global->LDS, 16B per lane; dst must be wave-uniform base (HW adds lane*16)
__device__ __forceinline__ void gld16(const us* src, us* dst){
  __builtin_amdgcn_global_load_lds(
      (const __attribute__((address_space(1))) unsigned int*)src,
      (__attribute__((address_space(3))) unsigned int*)dst, 16, 0, 0);
}

#define VM_WAIT4()   asm volatile("s_waitcnt vmcnt(4)" ::: "memory")
#define WAIT_ALL()   asm volatile("s_waitcnt vmcnt(0) lgkmcnt(0)" ::: "memory")
#define LGKM_WAIT0() asm volatile("s_waitcnt lgkmcnt(0)" ::: "memory")
#define BAR()        __builtin_amdgcn_s_barrier()
#define SCHED_FENCE() __builtin_amdgcn_sched_barrier(0)

// ---------------- 1) time_feature ----------------
__global__ __launch_bounds__(256) void tf_kernel(
    const float* __restrict__ seq, const float* __restrict__ Wsel,
    const float* __restrict__ bsel, const float* __restrict__ Wtime,
    const float* __restrict__ btime, float* __restrict__ tf)
{
  const int bt = blockIdx.x, tid = threadIdx.x;
  __shared__ float w1[64];
  float s = seq[bt];
  if (tid < 64){ float h = s*Wsel[tid] + bsel[tid]; w1[tid] = 1.0f - tanhf(h*h); }
  __syncthreads();
  const float* wrow = Wtime + (size_t)tid*64;
  float acc = btime[tid];
  #pragma unroll 8
  for (int j = 0; j < 64; ++j) acc += w1[j]*wrow[j];
  tf[(size_t)bt*256 + tid] = acc;
}

// ---------------- 2) embed + gate ----------------
struct GateLds {
  float E[32*260];
  float sc[64];
  float tfs[256];
  float gs[256];
};

template<int L, int N>
__device__ __forceinline__ void gate_body(GateLds& S,
    const int* __restrict__ codes, const float* __restrict__ mask,
    const float* __restrict__ emb, const float* __restrict__ tf,
    const float* __restrict__ Wg, const float* __restrict__ bg,
    us* __restrict__ Xg, us* __restrict__ XgT, float scale, int bt)
{
  const int b = bt/40, t = bt - (bt/40)*40;
  const int tid = threadIdx.x, lane = tid & 63, wid = tid >> 6;

  S.tfs[tid] = tf[(size_t)bt*256 + tid];
  #pragma unroll
  for (int l = 0; l < L; ++l){
    int code = codes[bt*L + l];
    float m = mask[bt*L + l];
    S.E[l*260 + tid] = emb[(size_t)code*256 + tid] * m;
  }
  __syncthreads();

  constexpr int RPW = (L + 3)/4;
  #pragma unroll
  for (int rr = 0; rr < RPW; ++rr){
    int l = wid*RPW + rr;
    if (l < L){
      f32x4 e4 = *(const f32x4*)&S.E[l*260 + lane*4];
      f32x4 t4 = *(const f32x4*)&S.tfs[lane*4];
      float p = dot4(e4, t4);
      #pragma unroll
      for (int m = 1; m < 64; m <<= 1) p += __shfl_xor(p, m, 64);
      if (lane == 0) S.sc[l] = p * scale;
    }
  }
  __syncthreads();
  if (wid == 0){
    float p = (lane < L) ? __expf(S.sc[lane]) : 0.f;
    float ss = p;
    #pragma unroll
    for (int m = 1; m < 64; m <<= 1) ss += __shfl_xor(ss, m, 64);
    if (lane < L) S.sc[lane] = p / ss;
  }
  __syncthreads();

  float g = 0.f;
  #pragma unroll
  for (int l = 0; l < L; ++l) g += S.sc[l]*S.E[l*260 + tid];
  S.gs[tid] = g;
  __syncthreads();

  const float* wrow = Wg + (size_t)tid*256;
  float a2 = bg[tid];
  #pragma unroll
  for (int e = 0; e < 256; e += 4){
    f32x4 w4 = *(const f32x4*)&wrow[e];
    f32x4 g4 = *(const f32x4*)&S.gs[e];
    a2 += dot4(w4, g4);
  }
  float g2 = 1.f/(1.f + __expf(-a2));

  us tbuf[L];
  #pragma unroll
  for (int l = 0; l < L; ++l){
    us h = f2bf(g2 * S.E[l*260 + tid]);
    Xg[((size_t)b*N + t*L + l)*256 + tid] = h;
    tbuf[l] = h;
  }
  size_t tb = ((size_t)b*256 + tid)*N + (size_t)t*L;
  #pragma unroll
  for (int l = 0; l < L; l += 8){
    uint4 v;
    v.x = (unsigned)tbuf[l+0] | ((unsigned)tbuf[l+1] << 16);
    v.y = (unsigned)tbuf[l+2] | ((unsigned)tbuf[l+3] << 16);
    v.z = (unsigned)tbuf[l+4] | ((unsigned)tbuf[l+5] << 16);
    v.w = (unsigned)tbuf[l+6] | ((unsigned)tbuf[l+7] << 16);
    *(uint4*)&XgT[tb + l] = v;
  }
}

template<int L, int N>
__global__ __launch_bounds__(256) void gate_kernel(
    const int* codes, const float* mask, const float* emb, const float* tf,
    const float* Wg, const float* bg, us* Xg, us* XgT, float scale)
{
  __shared__ GateLds S;
  gate_body<L,N>(S, codes, mask, emb, tf, Wg, bg, Xg, XgT, scale, blockIdx.x);
}

__global__ __launch_bounds__(256) void gate_fused(
    const int* mc, const int* dc, const int* pc,
    const float* mm, const float* dm, const float* pm,
    const float* em, const float* ed, const float* ep,
    const float* tf,
    const float* Wgm, const float* bgm, const float* Wgd, const float* bgd,
    const float* Wgp, const float* bgp,
    us* Xm, us* XTm, us* Xd, us* XTd, us* Xp, us* XTp, float scale)
{
  __shared__ GateLds S;
  int bid = blockIdx.x;
  if (bid < 1280)      gate_body<24,960 >(S, mc, mm, em, tf, Wgm, bgm, Xm, XTm, scale, bid);
  else if (bid < 2560) gate_body<32,1280>(S, dc, dm, ed, tf, Wgd, bgd, Xd, XTd, scale, bid-1280);
  else                 gate_body<16,640 >(S, pc, pm, ep, tf, Wgp, bgp, Xp, XTp, scale, bid-2560);
}

// ---------------- 3) visit self-attention (flash, bf16 MFMA) ----------------
// 44 KB LDS: single K buffer [32][256] swizzled, single V^T buffer [256][32]
// + ones tail rows [16][32], per-wave P scratch. 3-barrier counted-vmcnt
// schedule: K(t+1) staged under PV(t), V(t+1) staged after PV(t); vmcnt
// never drains freshly-issued K/V pair fully (vmcnt(4) leaves V in flight).
struct VisitLds {
  us ks[8192];     // K tile, rows 512B, XOR-swizzled (linear dest, pre-swz src)
  us vs[8704];     // V^T [256][32] + rows 256..271 (row 256 = ones)
  us ps[4*32*40];  // per-wave P scratch [32][40]
};

__device__ __forceinline__ void stage_K(VisitLds& S, const us* __restrict__ Xb,
                                        int k0, int tid)
{
  const int wid = tid >> 6;
  #pragma unroll
  for (int i = 0; i < 4; ++i){
    int c = tid + i*256;
    int row = c >> 5, ch = c & 31;
    gld16(Xb + (size_t)(k0 + row)*256 + (((ch*16) ^ ((row & 7) << 4)) >> 1),
          S.ks + (i*256 + wid*64)*8);
  }
}
__device__ __forceinline__ void stage_V(VisitLds& S, const us* __restrict__ XTb,
                                        int k0, int N_, int tid)
{
  const int wid = tid >> 6;
  #pragma unroll
  for (int i = 0; i < 4; ++i){
    int c = tid + i*256;
    int d = c >> 2, kslot = c & 3;
    gld16(XTb + (size_t)d*N_ + k0 + kslot*8, S.vs + (i*256 + wid*64)*8);
  }
}

template<int N>
__device__ __forceinline__ void visit_body(VisitLds& S,
    const us* __restrict__ Xb, const us* __restrict__ XTb,
    us* __restrict__ Outb, float scale, int q0)
{
  const int tid = threadIdx.x, lane = tid & 63, wid = tid >> 6;
  const int lc = lane & 15, lg = lane >> 4;

  // ---- direct-register Q loads ----
  s16x8 qf[2][8];
  #pragma unroll
  for (int qg = 0; qg < 2; ++qg)
    #pragma unroll
    for (int kk = 0; kk < 8; ++kk){
      int gr = q0 + wid*32 + qg*16 + lc;
      gr = gr < N ? gr : N-1;
      qf[qg][kk] = *(const s16x8*)(Xb + (size_t)gr*256 + kk*32 + lg*8);
    }

  // ones/zero tail rows of V buffer
  for (int i = tid; i < 512; i += 256)
    S.vs[8192 + i] = (i < 32) ? (us)0x3F80 : (us)0;

  // prologue: K(0) then V(0); pin issue order so vmcnt counting is exact
  SCHED_FENCE();
  stage_K(S, Xb, 0, tid);
  SCHED_FENCE();
  stage_V(S, XTb, 0, N, tid);
  SCHED_FENCE();
  VM_WAIT4();       // K(0) (and Q) landed; V(0)'s 4 may fly
  LGKM_WAIT0();     // ones-row writes done
  BAR();

  f32x4 o[2][16];
  #pragma unroll
  for (int qg = 0; qg < 2; ++qg)
    #pragma unroll
    for (int dcc = 0; dcc < 16; ++dcc) o[qg][dcc] = (f32x4){0.f,0.f,0.f,0.f};
  f32x4 ls[2] = {(f32x4){0.f,0.f,0.f,0.f}, (f32x4){0.f,0.f,0.f,0.f}};

  us* pw = S.ps + wid*32*40;
  const int nt = N/32;

  for (int t = 0; t < nt; ++t){
    // ---- S = Q K^T ----
    f32x4 s[2][2];
    #pragma unroll
    for (int qg = 0; qg < 2; ++qg)
      #pragma unroll
      for (int kc = 0; kc < 2; ++kc) s[qg][kc] = (f32x4){0.f,0.f,0.f,0.f};

    __builtin_amdgcn_s_setprio(1);
    #pragma unroll
    for (int kk = 0; kk < 8; ++kk){
      #pragma unroll
      for (int kc = 0; kc < 2; ++kc){
        int row = kc*16 + lc;
        int off = kk*64 + lg*16;
        s16x8 kb = *(const s16x8*)((const char*)S.ks + row*512 + (off ^ ((row & 7) << 4)));
        s[0][kc] = mfma16(qf[0][kk], kb, s[0][kc]);
        s[1][kc] = mfma16(qf[1][kk], kb, s[1][kc]);
      }
    }
    __builtin_amdgcn_s_setprio(0);

    // ---- softmax numerator -> bf16 P scratch -> A-fragments ----
    #pragma unroll
    for (int qg = 0; qg < 2; ++qg){
      #pragma unroll
      for (int r = 0; r < 4; ++r){
        float p0 = __expf(s[qg][0][r] * scale);
        float p1 = __expf(s[qg][1][r] * scale);
        int prow = qg*16 + lg*4 + r;
        pw[prow*40 + lc]      = f2bf(p0);
        pw[prow*40 + 16 + lc] = f2bf(p1);
      }
    }
    s16x8 pa[2];
    #pragma unroll
    for (int qg = 0; qg < 2; ++qg)
      pa[qg] = *(const s16x8*)(pw + (qg*16 + lc)*40 + lg*8);

    // KS reads retired + V(t) landed (issued a full iteration ago)
    WAIT_ALL();
    BAR();
    if (t + 1 < nt) stage_K(S, Xb, (t+1)*32, tid);   // overlaps PV

    // ---- O += P V ; row-sums via ones rows ----
    __builtin_amdgcn_s_setprio(1);
    #pragma unroll
    for (int dcc = 0; dcc < 16; ++dcc){
      s16x8 vf = *(const s16x8*)(S.vs + (dcc*16 + lc)*32 + lg*8);
      o[0][dcc] = mfma16(pa[0], vf, o[0][dcc]);
      o[1][dcc] = mfma16(pa[1], vf, o[1][dcc]);
    }
    {
      s16x8 vf1 = *(const s16x8*)(S.vs + (256 + lc)*32 + lg*8);
      ls[0] = mfma16(pa[0], vf1, ls[0]);
      ls[1] = mfma16(pa[1], vf1, ls[1]);
    }
    __builtin_amdgcn_s_setprio(0);

    if (t + 1 < nt){
      LGKM_WAIT0();          // PV's VS reads retired
      BAR();                 // all waves done with VS
      SCHED_FENCE();
      stage_V(S, XTb, (t+1)*32, N, tid);
      SCHED_FENCE();
      VM_WAIT4();            // K(t+1) landed (K issued before V); V(t+1) flies
      BAR();                 // K(t+1) visible to all before next QK
    }
  }

  // epilogue: normalize (lsum valid in lc==0 lanes; broadcast within lg group)
  #pragma unroll
  for (int qg = 0; qg < 2; ++qg){
    #pragma unroll
    for (int r = 0; r < 4; ++r){
      float lv = __shfl(ls[qg][r], lane & 48, 64);
      float inv = 1.f / lv;
      int grow = q0 + wid*32 + qg*16 + lg*4 + r;
      if (grow < N){
        #pragma unroll
        for (int dcc = 0; dcc < 16; ++dcc){
          Outb[(size_t)grow*256 + dcc*16 + lc] = f2bf(o[qg][dcc][r] * inv);
        }
      }
    }
  }
}

template<int N>
__global__ __launch_bounds__(256, 3) void visit_kernel(
    const us* Xg, const us* XgT, us* Out, float scale)
{
  __shared__ VisitLds S;
  const int b = blockIdx.y;
  visit_body<N>(S, Xg + (size_t)b*N*256, XgT + (size_t)b*256*N,
                Out + (size_t)b*N*256, scale, blockIdx.x*128);
}

__global__ __launch_bounds__(256, 3) void visit_fused(
    const us* Xm, const us* XTm, us* Am,
    const us* Xd, const us* XTd, us* Ad,
    const us* Xp, const us* XTp, us* Ap, float scale)
{
  __shared__ VisitLds S;
  // XCD-locality remap (736 = 8*92): contiguous logical chunk per XCD.
  // Work ordered longest-first: diag (40 tiles), med (30), proc (20).
  int p = blockIdx.x;
  int l = (p & 7)*92 + (p >> 3);
  if (l < 320){
    int b = l/10, q0 = (l - (l/10)*10)*128;
    visit_body<1280>(S, Xd + (size_t)b*1280*256, XTd + (size_t)b*256*1280,
                     Ad + (size_t)b*1280*256, scale, q0);
  } else if (l < 576){
    int r = l - 320, b = r >> 3, q0 = (r & 7)*128;
    visit_body<960>(S, Xm + (size_t)b*960*256, XTm + (size_t)b*256*960,
                    Am + (size_t)b*960*256, scale, q0);
  } else {
    int r = l - 576, b = r/5, q0 = (r - (r/5)*5)*128;
    visit_body<640>(S, Xp + (size_t)b*640*256, XTp + (size_t)b*256*640,
                    Ap + (size_t)b*640*256, scale, q0);
  }
}

// ---------------- 4) merge attention + med_att, fused per (b,t), all-MFMA GEMMs ----------------
// LDS 56.3 KB: A[80*256] holds Mb during phases 1-2, then is reused for
// Pb/W1B/wj/uk (phase 8 re-reads M from L2-warm global). SrB holds bf16 Sr,
// then aliases f32 S2.
__global__ __launch_bounds__(512, 4) void merge_kernel(
    const us* __restrict__ Amed, const us* __restrict__ Adiag,
    const us* __restrict__ Aproc, const float* __restrict__ tf,
    const float* __restrict__ bias, const int* __restrict__ ilen,
    float* __restrict__ out, float scale)
{
  __shared__ alignas(16) us A[80*256];    // 40960 B
  __shared__ alignas(16) us SrB[80*96];   // 15360 B
  us* Mb  = A;                             // phases 1-2 (dead after 2)
  us* Pb  = A;                             // phases 3+ (7680 shorts)
  us* W1B = A + 7680;                      // 3072 shorts
  float* wj  = (float*)(A + 10752);        // 73 floats
  float* uk  = (float*)(A + 10912);        // 73 floats
  float* S2f = (float*)SrB;                // aliases SrB after phase 4

  const int bt = blockIdx.x, b = bt/40, t = bt - (bt/40)*40;
  const int tid = threadIdx.x, lane = tid & 63, wid = tid >> 6;
  const int lc = lane & 15, lg = lane >> 4;

  // ---- phase 1: stage M (rows 0..71 bf16, row 72 = tf, rows 73..79 zero) ----
  for (int c = tid; c < 72*32; c += 512){
    int row = c >> 5, ch = c & 31;
    const us* src;
    if (row < 24)      src = Amed  + ((size_t)b*960  + t*24 + row)*256      + ch*8;
    else if (row < 56) src = Adiag + ((size_t)b*1280 + t*32 + (row-24))*256 + ch*8;
    else               src = Aproc + ((size_t)b*640  + t*16 + (row-56))*256 + ch*8;
    uint4 v = *(const uint4*)src;
    *(uint4*)((char*)Mb + row*512 + ((ch*16) ^ ((row & 7) << 4))) = v;
  }
  if (tid < 256) Mb[72*256 + tid] = f2bf(tf[(size_t)bt*256 + tid]);
  for (int c = tid; c < 7*32; c += 512){
    int row = 73 + (c >> 5), ch = c & 31;
    *(uint4*)((char*)Mb + row*512 + ch*16) = (uint4){0,0,0,0};
  }
  __syncthreads();

  // ---- phase 2: Sr = M M^T via MFMA (5x5 tiles, K=256), write bf16 ----
  for (int tt = wid; tt < 25; tt += 8){
    int ti = tt/5, tj = tt - (tt/5)*5;
    f32x4 s = (f32x4){0.f,0.f,0.f,0.f};
    #pragma unroll
    for (int kk = 0; kk < 8; ++kk){
      int ra = ti*16 + lc, rb = tj*16 + lc;
      int off = kk*64 + lg*16;
      s16x8 a  = *(const s16x8*)((const char*)Mb + ra*512 + (off ^ ((ra & 7) << 4)));
      s16x8 bb = *(const s16x8*)((const char*)Mb + rb*512 + (off ^ ((rb & 7) << 4)));
      s = mfma16(a, bb, s);
    }
    #pragma unroll
    for (int r = 0; r < 4; ++r)
      SrB[(ti*16 + lg*4 + r)*96 + tj*16 + lc] = f2bf(s[r]);
  }
  __syncthreads();   // Mb dead from here; A reused as Pb/W1B/wj/uk

  // ---- phase 3: P = row-softmax(scale*Sr) cols<73 -> bf16 Pb; pads zeroed ----
  for (int c = tid; c < 80*16; c += 512){                // SrB cols 80..95 := 0
    int r = c >> 4;
    SrB[r*96 + 80 + (c & 15)] = 0;
  }
  for (int r = wid; r < 73; r += 8){
    float e0 = __expf(scale * bf2f(SrB[r*96 + lane]));
    float e1 = (lane < 9) ? __expf(scale * bf2f(SrB[r*96 + 64 + lane])) : 0.f;
    float ss = e0 + e1;
    #pragma unroll
    for (int m = 1; m < 64; m <<= 1) ss += __shfl_xor(ss, m, 64);
    float inv = 1.f/ss;
    Pb[r*96 + lane] = f2bf(e0 * inv);
    if (lane < 32) Pb[r*96 + 64 + lane] = (lane < 9) ? f2bf(e1*inv) : (us)0;
  }
  for (int c = tid; c < 7*96; c += 512){                 // Pb rows 73..79 := 0
    Pb[73*96 + c] = 0;
  }
  __syncthreads();

  // ---- phase 4: W1 = P(0:32) * Sr via MFMA (Sr symmetric), K=96, bf16 ----
  for (int tt = wid; tt < 10; tt += 8){
    int ri = tt/5, cj = tt - (tt/5)*5;
    f32x4 s = (f32x4){0.f,0.f,0.f,0.f};
    #pragma unroll
    for (int kk = 0; kk < 3; ++kk){
      s16x8 a  = *(const s16x8*)(Pb  + (ri*16 + lc)*96 + kk*32 + lg*8);
      s16x8 bb = *(const s16x8*)(SrB + (cj*16 + lc)*96 + kk*32 + lg*8);
      s = mfma16(a, bb, s);
    }
    #pragma unroll
    for (int r = 0; r < 4; ++r)
      W1B[(ri*16 + lg*4 + r)*96 + cj*16 + lc] = f2bf(s[r]);
  }
  if (tid < 512){                                        // W1B cols 80..95 := 0
    W1B[(tid >> 4)*96 + 80 + (tid & 15)] = 0;
  }
  __syncthreads();

  // ---- phase 5: S2 = W1 * P^T via MFMA, K=96, f32 into S2f (aliases SrB) ----
  for (int tt = wid; tt < 10; tt += 8){
    int ri = tt/5, cj = tt - (tt/5)*5;
    f32x4 s = (f32x4){0.f,0.f,0.f,0.f};
    #pragma unroll
    for (int kk = 0; kk < 3; ++kk){
      s16x8 a  = *(const s16x8*)(W1B + (ri*16 + lc)*96 + kk*32 + lg*8);
      s16x8 bb = *(const s16x8*)(Pb  + (cj*16 + lc)*96 + kk*32 + lg*8);
      s = mfma16(a, bb, s);
    }
    #pragma unroll
    for (int r = 0; r < 4; ++r)
      S2f[(ri*16 + lg*4 + r)*84 + cj*16 + lc] = s[r];
  }
  __syncthreads();

  // ---- phase 6: P2 = row-softmax(S2) rows<24, in place ----
  for (int r = wid; r < 24; r += 8){
    float e0 = __expf(S2f[r*84 + lane]);
    float e1 = (lane < 9) ? __expf(S2f[r*84 + 64 + lane]) : 0.f;
    float ss = e0 + e1;
    #pragma unroll
    for (int m = 1; m < 64; m <<= 1) ss += __shfl_xor(ss, m, 64);
    float inv = 1.f/ss;
    S2f[r*84 + lane] = e0*inv;
    if (lane < 12) S2f[r*84 + 64 + lane] = (lane < 9) ? e1*inv : 0.f;
  }
  __syncthreads();

  // ---- phase 7: wj, then uk ----
  if (tid < 73){
    float a = 0.f;
    #pragma unroll
    for (int i = 0; i < 24; ++i) a += S2f[i*84 + tid];
    wj[tid] = a;
  }
  __syncthreads();
  if (tid < 73){
    float a = 0.f;
    for (int j = 0; j < 73; ++j) a += wj[j] * bf2f(Pb[j*96 + tid]);
    uk[tid] = a;
  }
  __syncthreads();

  // ---- phase 8: out = bias + pos + sum_k uk[k]*M[k] (M re-read, L2-warm) ----
  if (tid < 256){
    float acc = bias[tid];
    if (t < ilen[b]){
      float ex = (float)(2*(tid>>1)) * (1.0f/256.0f);
      float dv = powf(10000.f, ex);
      float ang = (float)t / dv;
      acc += (tid & 1) ? cosf(ang) : sinf(ang);
    }
    const us* Am_ = Amed  + ((size_t)b*960  + t*24)*256 + tid;
    #pragma unroll 4
    for (int k = 0; k < 24; ++k) acc += uk[k]      * bf2f(Am_[k*256]);
    const us* Ad_ = Adiag + ((size_t)b*1280 + t*32)*256 + tid;
    #pragma unroll 4
    for (int k = 0; k < 32; ++k) acc += uk[24 + k] * bf2f(Ad_[k*256]);
    const us* Ap_ = Aproc + ((size_t)b*640  + t*16)*256 + tid;
    #pragma unroll 4
    for (int k = 0; k < 16; ++k) acc += uk[56 + k] * bf2f(Ap_[k*256]);
    acc += uk[72] * tf[(size_t)bt*256 + tid];
    out[(size_t)bt*256 + tid] = acc;
  }
}

// ---------------- launch ----------------
extern "C" void kernel_launch(void* const* d_in, const int* in_sizes, int n_in,
                              void* d_out, int out_size, void* d_ws, size_t ws_size,
                              hipStream_t stream)
{
  (void)in_sizes; (void)n_in; (void)out_size;

  const int*   med_codes = (const int*)  d_in[0];
  const int*   diag_codes= (const int*)  d_in[1];
  const int*   proc_codes= (const int*)  d_in[2];
  const float* med_mask  = (const float*)d_in[3];
  const float* diag_mask = (const float*)d_in[4];
  const float* proc_mask = (const float*)d_in[5];
  const float* seq_time  = (const float*)d_in[6];
  const int*   input_len = (const int*)  d_in[7];
  const float* emb_med   = (const float*)d_in[8];
  const float* emb_diag  = (const float*)d_in[9];
  const float* emb_proc  = (const float*)d_in[10];
  const float* bias_med  = (const float*)d_in[11];
  const float* W_sel     = (const float*)d_in[12];
  const float* b_sel     = (const float*)d_in[13];
  const float* W_time    = (const float*)d_in[14];
  const float* b_time    = (const float*)d_in[15];
  const float* Wg_med    = (const float*)d_in[16];
  const float* bg_med    = (const float*)d_in[17];
  const float* Wg_diag   = (const float*)d_in[18];
  const float* bg_diag   = (const float*)d_in[19];
  const float* Wg_proc   = (const float*)d_in[20];
  const float* bg_proc   = (const float*)d_in[21];

  const float scale = (float)(1.0 / sqrt(256.0 + 1e-7));

  char* ws = (char*)d_ws;
  const size_t sz_tf = (size_t)1280*256*4;
  const size_t szA_m = (size_t)32*960*256*2;
  const size_t szA_d = (size_t)32*1280*256*2;
  const size_t szA_p = (size_t)32*640*256*2;

  size_t off = 0;
  float* tf   = (float*)(ws + off); off += sz_tf;
  us* Am      = (us*)(ws + off);    off += szA_m;
  us* Ad      = (us*)(ws + off);    off += szA_d;
  us* Ap      = (us*)(ws + off);    off += szA_p;

  const size_t fused_need = off + 2*(szA_m + szA_d + szA_p);
  tf_kernel<<<1280, 256, 0, stream>>>(seq_time, W_sel, b_sel, W_time, b_time, tf);

  if (ws_size >= fused_need){
    us* Xm  = (us*)(ws + off); off += szA_m;
    us* XTm = (us*)(ws + off); off += szA_m;
    us* Xd  = (us*)(ws + off); off += szA_d;
    us* XTd = (us*)(ws + off); off += szA_d;
    us* Xp  = (us*)(ws + off); off += szA_p;
    us* XTp = (us*)(ws + off); off += szA_p;

    gate_fused<<<3840, 256, 0, stream>>>(
        med_codes, diag_codes, proc_codes, med_mask, diag_mask, proc_mask,
        emb_med, emb_diag, emb_proc, tf,
        Wg_med, bg_med, Wg_diag, bg_diag, Wg_proc, bg_proc,
        Xm, XTm, Xd, XTd, Xp, XTp, scale);

    visit_fused<<<736, 256, 0, stream>>>(Xm, XTm, Am, Xd, XTd, Ad, Xp, XTp, Ap, scale);
  } else {
    us* Xg  = (us*)(ws + off);
    us* XgT = (us*)(ws + off + szA_d);

    gate_kernel<24,960><<<1280, 256, 0, stream>>>(med_codes, med_mask, emb_med, tf, Wg_med, bg_med, Xg, XgT, scale);
    visit_kernel<960><<<dim3(8,32), 256, 0, stream>>>(Xg, XgT, Am, scale);

    gate_kernel<32,1280><<<1280, 256, 0, stream>>>(diag_codes, diag_mask, emb_diag, tf, Wg_diag, bg_diag, Xg, XgT, scale);
    visit_kernel<1280><<<dim3(10,32), 256, 0, stream>>>(Xg, XgT, Ad, scale);

    gate_kernel<16,640><<<1280, 256, 0, stream>>>(proc_codes, proc_mask, emb_proc, tf, Wg_proc, bg_proc, Xg, XgT, scale);
    visit_kernel<640><<<dim3(5,32), 256, 0, stream>>>(Xg, XgT, Ap, scale);
  }

  merge_kernel<<<1280, 512, 0, stream>>>(Am, Ad, Ap, tf, bias_med, input_len, (float*)d_out, scale);
}

// Round 6
// 447.682 us; speedup vs baseline: 1.6198x; 1.6198x over previous
//
#include <hip/hip_runtime.h>
#include <hip/hip_bf16.h>
#include <math.h>

// ---------------- types / helpers ----------------
typedef float f32x4 __attribute__((ext_vector_type(4)));
typedef short s16x8 __attribute__((ext_vector_type(8)));
typedef unsigned short us;

__device__ __forceinline__ float bf2f(us u){
  union { unsigned int i; float f; } v; v.i = ((unsigned int)u) << 16; return v.f;
}
__device__ __forceinline__ us f2bf(float f){
  union { float f; unsigned int i; } v; v.f = f;
  unsigned int r = v.i + 0x7FFFu + ((v.i >> 16) & 1u);
  return (us)(r >> 16);
}
__device__ __forceinline__ float dot4(f32x4 a, f32x4 b){
  return a.x*b.x + a.y*b.y + a.z*b.z + a.w*b.w;
}
__device__ __forceinline__ f32x4 mfma16(s16x8 a, s16x8 b, f32x4 c){
  return __builtin_amdgcn_mfma_f32_16x16x32_bf16(a, b, c, 0, 0, 0);
}
// async global->LDS, 16B per lane; dst must be wave-uniform base (HW adds lane*16)
__device__ __forceinline__ void gld16(const us* src, us* dst){
  __builtin_amdgcn_global_load_lds(
      (const __attribute__((address_space(1))) unsigned int*)src,
      (__attribute__((address_space(3))) unsigned int*)dst, 16, 0, 0);
}

#define VM_WAIT16()  asm volatile("s_waitcnt vmcnt(16)" ::: "memory")
#define VM_WAIT0()   asm volatile("s_waitcnt vmcnt(0)" ::: "memory")
#define LGKM_WAIT0() asm volatile("s_waitcnt lgkmcnt(0)" ::: "memory")
#define PRO_WAIT()   asm volatile("s_waitcnt vmcnt(16) lgkmcnt(0)" ::: "memory")
#define BAR()        __builtin_amdgcn_s_barrier()
#define SCHED_FENCE() __builtin_amdgcn_sched_barrier(0)

// ---------------- 1) time_feature ----------------
__global__ __launch_bounds__(256) void tf_kernel(
    const float* __restrict__ seq, const float* __restrict__ Wsel,
    const float* __restrict__ bsel, const float* __restrict__ Wtime,
    const float* __restrict__ btime, float* __restrict__ tf)
{
  const int bt = blockIdx.x, tid = threadIdx.x;
  __shared__ float w1[64];
  float s = seq[bt];
  if (tid < 64){ float h = s*Wsel[tid] + bsel[tid]; w1[tid] = 1.0f - tanhf(h*h); }
  __syncthreads();
  const float* wrow = Wtime + (size_t)tid*64;
  float acc = btime[tid];
  #pragma unroll 8
  for (int j = 0; j < 64; ++j) acc += w1[j]*wrow[j];
  tf[(size_t)bt*256 + tid] = acc;
}

// ---------------- 2) embed + gate ----------------
struct GateLds {
  float E[32*260];
  float sc[64];
  float tfs[256];
  float gs[256];
};

template<int L, int N>
__device__ __forceinline__ void gate_body(GateLds& S,
    const int* __restrict__ codes, const float* __restrict__ mask,
    const float* __restrict__ emb, const float* __restrict__ tf,
    const float* __restrict__ Wg, const float* __restrict__ bg,
    us* __restrict__ Xg, us* __restrict__ XgT, float scale, int bt)
{
  const int b = bt/40, t = bt - (bt/40)*40;
  const int tid = threadIdx.x, lane = tid & 63, wid = tid >> 6;

  S.tfs[tid] = tf[(size_t)bt*256 + tid];
  #pragma unroll
  for (int l = 0; l < L; ++l){
    int code = codes[bt*L + l];
    float m = mask[bt*L + l];
    S.E[l*260 + tid] = emb[(size_t)code*256 + tid] * m;
  }
  __syncthreads();

  constexpr int RPW = (L + 3)/4;
  #pragma unroll
  for (int rr = 0; rr < RPW; ++rr){
    int l = wid*RPW + rr;
    if (l < L){
      f32x4 e4 = *(const f32x4*)&S.E[l*260 + lane*4];
      f32x4 t4 = *(const f32x4*)&S.tfs[lane*4];
      float p = dot4(e4, t4);
      #pragma unroll
      for (int m = 1; m < 64; m <<= 1) p += __shfl_xor(p, m, 64);
      if (lane == 0) S.sc[l] = p * scale;
    }
  }
  __syncthreads();
  if (wid == 0){
    float p = (lane < L) ? __expf(S.sc[lane]) : 0.f;
    float ss = p;
    #pragma unroll
    for (int m = 1; m < 64; m <<= 1) ss += __shfl_xor(ss, m, 64);
    if (lane < L) S.sc[lane] = p / ss;
  }
  __syncthreads();

  float g = 0.f;
  #pragma unroll
  for (int l = 0; l < L; ++l) g += S.sc[l]*S.E[l*260 + tid];
  S.gs[tid] = g;
  __syncthreads();

  const float* wrow = Wg + (size_t)tid*256;
  float a2 = bg[tid];
  #pragma unroll
  for (int e = 0; e < 256; e += 4){
    f32x4 w4 = *(const f32x4*)&wrow[e];
    f32x4 g4 = *(const f32x4*)&S.gs[e];
    a2 += dot4(w4, g4);
  }
  float g2 = 1.f/(1.f + __expf(-a2));

  us tbuf[L];
  #pragma unroll
  for (int l = 0; l < L; ++l){
    us h = f2bf(g2 * S.E[l*260 + tid]);
    Xg[((size_t)b*N + t*L + l)*256 + tid] = h;
    tbuf[l] = h;
  }
  size_t tb = ((size_t)b*256 + tid)*N + (size_t)t*L;
  #pragma unroll
  for (int l = 0; l < L; l += 8){
    uint4 v;
    v.x = (unsigned)tbuf[l+0] | ((unsigned)tbuf[l+1] << 16);
    v.y = (unsigned)tbuf[l+2] | ((unsigned)tbuf[l+3] << 16);
    v.z = (unsigned)tbuf[l+4] | ((unsigned)tbuf[l+5] << 16);
    v.w = (unsigned)tbuf[l+6] | ((unsigned)tbuf[l+7] << 16);
    *(uint4*)&XgT[tb + l] = v;
  }
}

template<int L, int N>
__global__ __launch_bounds__(256) void gate_kernel(
    const int* codes, const float* mask, const float* emb, const float* tf,
    const float* Wg, const float* bg, us* Xg, us* XgT, float scale)
{
  __shared__ GateLds S;
  gate_body<L,N>(S, codes, mask, emb, tf, Wg, bg, Xg, XgT, scale, blockIdx.x);
}

__global__ __launch_bounds__(256) void gate_fused(
    const int* mc, const int* dc, const int* pc,
    const float* mm, const float* dm, const float* pm,
    const float* em, const float* ed, const float* ep,
    const float* tf,
    const float* Wgm, const float* bgm, const float* Wgd, const float* bgd,
    const float* Wgp, const float* bgp,
    us* Xm, us* XTm, us* Xd, us* XTd, us* Xp, us* XTp, float scale)
{
  __shared__ GateLds S;
  int bid = blockIdx.x;
  if (bid < 1280)      gate_body<24,960 >(S, mc, mm, em, tf, Wgm, bgm, Xm, XTm, scale, bid);
  else if (bid < 2560) gate_body<32,1280>(S, dc, dm, ed, tf, Wgd, bgd, Xd, XTd, scale, bid-1280);
  else                 gate_body<16,640 >(S, pc, pm, ep, tf, Wgp, bgp, Xp, XTp, scale, bid-2560);
}

// ---------------- 3) visit self-attention (flash, bf16 MFMA, KVBLK=64) ----------------
// 148 KB LDS, intentionally 1 block/CU (L2 working set per XCD must stay
// within ~4 MB -- round-5 lesson: 2 blocks/CU thrashed L2, FETCH 64MB->1.27GB).
// Double-buffered 64-row K/V tiles, 2-deep prefetch, counted vmcnt(16).
// K rows XOR-swizzled (byte ^ (row&7)<<4) via pre-swizzled global chunks;
// V^T rows ([256][64], 128B rows) likewise swizzled -> 2-way-max bank aliasing.
struct VisitLds {
  us ks[2][16384];   // K tiles: 64 rows x 512B, swizzled
  us vs[2][16384];   // V^T tiles: 256 rows x 128B, swizzled
  us ones[1024];     // 16 rows x 64: row 0 = ones (swizzle-invariant)
  us ps[4*32*72];    // per-wave P scratch [32][72]
};

__device__ __forceinline__ void stage_K(VisitLds& S, int cur,
    const us* __restrict__ Xb, int k0, int tid)
{
  const int wid = tid >> 6;
  #pragma unroll
  for (int i = 0; i < 8; ++i){
    int c = tid + i*256;
    int row = c >> 5, ch = c & 31;
    gld16(Xb + (size_t)(k0 + row)*256 + (((ch*16) ^ ((row & 7) << 4)) >> 1),
          S.ks[cur] + (i*256 + wid*64)*8);
  }
}
__device__ __forceinline__ void stage_V(VisitLds& S, int cur,
    const us* __restrict__ XTb, int k0, int N_, int tid)
{
  const int wid = tid >> 6;
  #pragma unroll
  for (int i = 0; i < 8; ++i){
    int c = tid + i*256;
    int d = c >> 3, chunk = c & 7;
    gld16(XTb + (size_t)d*N_ + k0 + ((chunk ^ (d & 7))*8),
          S.vs[cur] + (i*256 + wid*64)*8);
  }
}

template<int N>
__device__ __forceinline__ void visit_body(VisitLds& S,
    const us* __restrict__ Xb, const us* __restrict__ XTb,
    us* __restrict__ Outb, float scale, int q0)
{
  const int tid = threadIdx.x, lane = tid & 63, wid = tid >> 6;
  const int lc = lane & 15, lg = lane >> 4;

  // ---- direct-register Q loads ----
  s16x8 qf[2][8];
  #pragma unroll
  for (int qg = 0; qg < 2; ++qg)
    #pragma unroll
    for (int kk = 0; kk < 8; ++kk){
      int gr = q0 + wid*32 + qg*16 + lc;
      gr = gr < N ? gr : N-1;
      qf[qg][kk] = *(const s16x8*)(Xb + (size_t)gr*256 + kk*32 + lg*8);
    }

  // ones region (row 0 = 1.0bf16, rows 1..15 = 0); swizzle-invariant by rows
  for (int i = tid; i < 1024; i += 256)
    S.ones[i] = (i < 64) ? (us)0x3F80 : (us)0;

  // prologue: 2-deep prefetch (16 gld16 per tile; Q loads drain with first wait)
  stage_K(S, 0, Xb, 0, tid);
  stage_V(S, 0, XTb, 0, N, tid);
  stage_K(S, 1, Xb, 64, tid);
  stage_V(S, 1, XTb, 64, N, tid);
  PRO_WAIT();        // tile 0 (and Q) landed; tile 1's 16 may fly; ones written
  BAR();

  f32x4 o[2][16];
  #pragma unroll
  for (int qg = 0; qg < 2; ++qg)
    #pragma unroll
    for (int dcc = 0; dcc < 16; ++dcc) o[qg][dcc] = (f32x4){0.f,0.f,0.f,0.f};
  f32x4 ls[2] = {(f32x4){0.f,0.f,0.f,0.f}, (f32x4){0.f,0.f,0.f,0.f}};

  us* pw = S.ps + wid*32*72;
  const int nt = N/64;

  for (int t = 0; t < nt; ++t){
    const int cur = t & 1;
    // ---- S = Q K^T (64-wide) ----
    f32x4 s[2][4];
    #pragma unroll
    for (int qg = 0; qg < 2; ++qg)
      #pragma unroll
      for (int kc = 0; kc < 4; ++kc) s[qg][kc] = (f32x4){0.f,0.f,0.f,0.f};

    __builtin_amdgcn_s_setprio(1);
    #pragma unroll
    for (int kk = 0; kk < 8; ++kk){
      #pragma unroll
      for (int kc = 0; kc < 4; ++kc){
        int row = kc*16 + lc;
        int off = kk*64 + lg*16;
        s16x8 kb = *(const s16x8*)((const char*)S.ks[cur] + row*512 + (off ^ ((row & 7) << 4)));
        s[0][kc] = mfma16(qf[0][kk], kb, s[0][kc]);
        s[1][kc] = mfma16(qf[1][kk], kb, s[1][kc]);
      }
    }
    __builtin_amdgcn_s_setprio(0);

    // ---- softmax numerator -> bf16 P scratch ----
    #pragma unroll
    for (int qg = 0; qg < 2; ++qg){
      #pragma unroll
      for (int r = 0; r < 4; ++r){
        int prow = qg*16 + lg*4 + r;
        #pragma unroll
        for (int kc = 0; kc < 4; ++kc){
          float p = __expf(s[qg][kc][r] * scale);
          pw[prow*72 + kc*16 + lc] = f2bf(p);
        }
      }
    }
    s16x8 pa[2][2];
    #pragma unroll
    for (int qg = 0; qg < 2; ++qg)
      #pragma unroll
      for (int ks = 0; ks < 2; ++ks)
        pa[qg][ks] = *(const s16x8*)(pw + (qg*16 + lc)*72 + ks*32 + lg*8);

    // ---- O += P V ; row-sums via ones rows ----
    __builtin_amdgcn_s_setprio(1);
    #pragma unroll
    for (int dcc = 0; dcc < 16; ++dcc){
      int d = dcc*16 + lc;
      s16x8 vf0 = *(const s16x8*)((const char*)S.vs[cur] + ((d*128 + 0*64 + lg*16) ^ ((d & 7) << 4)));
      s16x8 vf1 = *(const s16x8*)((const char*)S.vs[cur] + ((d*128 + 1*64 + lg*16) ^ ((d & 7) << 4)));
      o[0][dcc] = mfma16(pa[0][0], vf0, o[0][dcc]);
      o[1][dcc] = mfma16(pa[1][0], vf0, o[1][dcc]);
      o[0][dcc] = mfma16(pa[0][1], vf1, o[0][dcc]);
      o[1][dcc] = mfma16(pa[1][1], vf1, o[1][dcc]);
    }
    #pragma unroll
    for (int ks = 0; ks < 2; ++ks){
      s16x8 of = *(const s16x8*)((const char*)S.ones + ((lc*128 + ks*64 + lg*16) ^ ((lc & 7) << 4)));
      ls[0] = mfma16(pa[0][ks], of, ls[0]);
      ls[1] = mfma16(pa[1][ks], of, ls[1]);
    }
    __builtin_amdgcn_s_setprio(0);

    if (t + 1 == nt) break;
    SCHED_FENCE();
    LGKM_WAIT0();              // this wave's K/V reads retired into regs
    BAR();                     // all waves done reading buf[cur]
    if (t + 2 < nt){
      stage_K(S, cur, Xb, (t+2)*64, tid);
      stage_V(S, cur, XTb, (t+2)*64, N, tid);
      VM_WAIT16();             // tile t+1 fully landed; t+2's 16 may fly
    } else {
      VM_WAIT0();              // drain to guarantee t+1
    }
    BAR();                     // tile t+1 visible to all waves
    SCHED_FENCE();
  }

  // epilogue: normalize (lsum valid in lc==0 lanes; broadcast within lg group)
  #pragma unroll
  for (int qg = 0; qg < 2; ++qg){
    #pragma unroll
    for (int r = 0; r < 4; ++r){
      float lv = __shfl(ls[qg][r], lane & 48, 64);
      float inv = 1.f / lv;
      int grow = q0 + wid*32 + qg*16 + lg*4 + r;
      if (grow < N){
        #pragma unroll
        for (int dcc = 0; dcc < 16; ++dcc){
          Outb[(size_t)grow*256 + dcc*16 + lc] = f2bf(o[qg][dcc][r] * inv);
        }
      }
    }
  }
}

template<int N>
__global__ __launch_bounds__(256) void visit_kernel(
    const us* Xg, const us* XgT, us* Out, float scale)
{
  __shared__ VisitLds S;
  const int b = blockIdx.y;
  visit_body<N>(S, Xg + (size_t)b*N*256, XgT + (size_t)b*256*N,
                Out + (size_t)b*N*256, scale, blockIdx.x*128);
}

__global__ __launch_bounds__(256) void visit_fused(
    const us* Xm, const us* XTm, us* Am,
    const us* Xd, const us* XTd, us* Ad,
    const us* Xp, const us* XTp, us* Ap, float scale)
{
  __shared__ VisitLds S;
  // XCD-locality remap (736 = 8*92): contiguous logical chunk per XCD.
  // Longest-first: diag (20 KV-iters), med (15), proc (10).
  int p = blockIdx.x;
  int l = (p & 7)*92 + (p >> 3);
  if (l < 320){
    int b = l/10, q0 = (l - (l/10)*10)*128;
    visit_body<1280>(S, Xd + (size_t)b*1280*256, XTd + (size_t)b*256*1280,
                     Ad + (size_t)b*1280*256, scale, q0);
  } else if (l < 576){
    int r = l - 320, b = r >> 3, q0 = (r & 7)*128;
    visit_body<960>(S, Xm + (size_t)b*960*256, XTm + (size_t)b*256*960,
                    Am + (size_t)b*960*256, scale, q0);
  } else {
    int r = l - 576, b = r/5, q0 = (r - (r/5)*5)*128;
    visit_body<640>(S, Xp + (size_t)b*640*256, XTp + (size_t)b*256*640,
                    Ap + (size_t)b*640*256, scale, q0);
  }
}

// ---------------- 4) merge attention + med_att, fused per (b,t), all-MFMA GEMMs ----------------
__global__ __launch_bounds__(512, 4) void merge_kernel(
    const us* __restrict__ Amed, const us* __restrict__ Adiag,
    const us* __restrict__ Aproc, const float* __restrict__ tf,
    const float* __restrict__ bias, const int* __restrict__ ilen,
    float* __restrict__ out, float scale)
{
  __shared__ alignas(16) us A[80*256];    // 40960 B
  __shared__ alignas(16) us SrB[80*96];   // 15360 B
  us* Mb  = A;                             // phases 1-2 (dead after 2)
  us* Pb  = A;                             // phases 3+ (7680 shorts)
  us* W1B = A + 7680;                      // 3072 shorts
  float* wj  = (float*)(A + 10752);        // 73 floats
  float* uk  = (float*)(A + 10912);        // 73 floats
  float* S2f = (float*)SrB;                // aliases SrB after phase 4

  const int bt = blockIdx.x, b = bt/40, t = bt - (bt/40)*40;
  const int tid = threadIdx.x, lane = tid & 63, wid = tid >> 6;
  const int lc = lane & 15, lg = lane >> 4;

  for (int c = tid; c < 72*32; c += 512){
    int row = c >> 5, ch = c & 31;
    const us* src;
    if (row < 24)      src = Amed  + ((size_t)b*960  + t*24 + row)*256      + ch*8;
    else if (row < 56) src = Adiag + ((size_t)b*1280 + t*32 + (row-24))*256 + ch*8;
    else               src = Aproc + ((size_t)b*640  + t*16 + (row-56))*256 + ch*8;
    uint4 v = *(const uint4*)src;
    *(uint4*)((char*)Mb + row*512 + ((ch*16) ^ ((row & 7) << 4))) = v;
  }
  if (tid < 256) Mb[72*256 + tid] = f2bf(tf[(size_t)bt*256 + tid]);
  for (int c = tid; c < 7*32; c += 512){
    int row = 73 + (c >> 5), ch = c & 31;
    *(uint4*)((char*)Mb + row*512 + ch*16) = (uint4){0,0,0,0};
  }
  __syncthreads();

  for (int tt = wid; tt < 25; tt += 8){
    int ti = tt/5, tj = tt - (tt/5)*5;
    f32x4 s = (f32x4){0.f,0.f,0.f,0.f};
    #pragma unroll
    for (int kk = 0; kk < 8; ++kk){
      int ra = ti*16 + lc, rb = tj*16 + lc;
      int off = kk*64 + lg*16;
      s16x8 a  = *(const s16x8*)((const char*)Mb + ra*512 + (off ^ ((ra & 7) << 4)));
      s16x8 bb = *(const s16x8*)((const char*)Mb + rb*512 + (off ^ ((rb & 7) << 4)));
      s = mfma16(a, bb, s);
    }
    #pragma unroll
    for (int r = 0; r < 4; ++r)
      SrB[(ti*16 + lg*4 + r)*96 + tj*16 + lc] = f2bf(s[r]);
  }
  __syncthreads();   // Mb dead from here; A reused as Pb/W1B/wj/uk

  for (int c = tid; c < 80*16; c += 512){
    int r = c >> 4;
    SrB[r*96 + 80 + (c & 15)] = 0;
  }
  for (int r = wid; r < 73; r += 8){
    float e0 = __expf(scale * bf2f(SrB[r*96 + lane]));
    float e1 = (lane < 9) ? __expf(scale * bf2f(SrB[r*96 + 64 + lane])) : 0.f;
    float ss = e0 + e1;
    #pragma unroll
    for (int m = 1; m < 64; m <<= 1) ss += __shfl_xor(ss, m, 64);
    float inv = 1.f/ss;
    Pb[r*96 + lane] = f2bf(e0 * inv);
    if (lane < 32) Pb[r*96 + 64 + lane] = (lane < 9) ? f2bf(e1*inv) : (us)0;
  }
  for (int c = tid; c < 7*96; c += 512){
    Pb[73*96 + c] = 0;
  }
  __syncthreads();

  for (int tt = wid; tt < 10; tt += 8){
    int ri = tt/5, cj = tt - (tt/5)*5;
    f32x4 s = (f32x4){0.f,0.f,0.f,0.f};
    #pragma unroll
    for (int kk = 0; kk < 3; ++kk){
      s16x8 a  = *(const s16x8*)(Pb  + (ri*16 + lc)*96 + kk*32 + lg*8);
      s16x8 bb = *(const s16x8*)(SrB + (cj*16 + lc)*96 + kk*32 + lg*8);
      s = mfma16(a, bb, s);
    }
    #pragma unroll
    for (int r = 0; r < 4; ++r)
      W1B[(ri*16 + lg*4 + r)*96 + cj*16 + lc] = f2bf(s[r]);
  }
  if (tid < 512){
    W1B[(tid >> 4)*96 + 80 + (tid & 15)] = 0;
  }
  __syncthreads();

  for (int tt = wid; tt < 10; tt += 8){
    int ri = tt/5, cj = tt - (tt/5)*5;
    f32x4 s = (f32x4){0.f,0.f,0.f,0.f};
    #pragma unroll
    for (int kk = 0; kk < 3; ++kk){
      s16x8 a  = *(const s16x8*)(W1B + (ri*16 + lc)*96 + kk*32 + lg*8);
      s16x8 bb = *(const s16x8*)(Pb  + (cj*16 + lc)*96 + kk*32 + lg*8);
      s = mfma16(a, bb, s);
    }
    #pragma unroll
    for (int r = 0; r < 4; ++r)
      S2f[(ri*16 + lg*4 + r)*84 + cj*16 + lc] = s[r];
  }
  __syncthreads();

  for (int r = wid; r < 24; r += 8){
    float e0 = __expf(S2f[r*84 + lane]);
    float e1 = (lane < 9) ? __expf(S2f[r*84 + 64 + lane]) : 0.f;
    float ss = e0 + e1;
    #pragma unroll
    for (int m = 1; m < 64; m <<= 1) ss += __shfl_xor(ss, m, 64);
    float inv = 1.f/ss;
    S2f[r*84 + lane] = e0*inv;
    if (lane < 12) S2f[r*84 + 64 + lane] = (lane < 9) ? e1*inv : 0.f;
  }
  __syncthreads();

  if (tid < 73){
    float a = 0.f;
    #pragma unroll
    for (int i = 0; i < 24; ++i) a += S2f[i*84 + tid];
    wj[tid] = a;
  }
  __syncthreads();
  if (tid < 73){
    float a = 0.f;
    for (int j = 0; j < 73; ++j) a += wj[j] * bf2f(Pb[j*96 + tid]);
    uk[tid] = a;
  }
  __syncthreads();

  if (tid < 256){
    float acc = bias[tid];
    if (t < ilen[b]){
      float ex = (float)(2*(tid>>1)) * (1.0f/256.0f);
      float dv = powf(10000.f, ex);
      float ang = (float)t / dv;
      acc += (tid & 1) ? cosf(ang) : sinf(ang);
    }
    const us* Am_ = Amed  + ((size_t)b*960  + t*24)*256 + tid;
    #pragma unroll 4
    for (int k = 0; k < 24; ++k) acc += uk[k]      * bf2f(Am_[k*256]);
    const us* Ad_ = Adiag + ((size_t)b*1280 + t*32)*256 + tid;
    #pragma unroll 4
    for (int k = 0; k < 32; ++k) acc += uk[24 + k] * bf2f(Ad_[k*256]);
    const us* Ap_ = Aproc + ((size_t)b*640  + t*16)*256 + tid;
    #pragma unroll 4
    for (int k = 0; k < 16; ++k) acc += uk[56 + k] * bf2f(Ap_[k*256]);
    acc += uk[72] * tf[(size_t)bt*256 + tid];
    out[(size_t)bt*256 + tid] = acc;
  }
}

// ---------------- launch ----------------
extern "C" void kernel_launch(void* const* d_in, const int* in_sizes, int n_in,
                              void* d_out, int out_size, void* d_ws, size_t ws_size,
                              hipStream_t stream)
{
  (void)in_sizes; (void)n_in; (void)out_size;

  const int*   med_codes = (const int*)  d_in[0];
  const int*   diag_codes= (const int*)  d_in[1];
  const int*   proc_codes= (const int*)  d_in[2];
  const float* med_mask  = (const float*)d_in[3];
  const float* diag_mask = (const float*)d_in[4];
  const float* proc_mask = (const float*)d_in[5];
  const float* seq_time  = (const float*)d_in[6];
  const int*   input_len = (const int*)  d_in[7];
  const float* emb_med   = (const float*)d_in[8];
  const float* emb_diag  = (const float*)d_in[9];
  const float* emb_proc  = (const float*)d_in[10];
  const float* bias_med  = (const float*)d_in[11];
  const float* W_sel     = (const float*)d_in[12];
  const float* b_sel     = (const float*)d_in[13];
  const float* W_time    = (const float*)d_in[14];
  const float* b_time    = (const float*)d_in[15];
  const float* Wg_med    = (const float*)d_in[16];
  const float* bg_med    = (const float*)d_in[17];
  const float* Wg_diag   = (const float*)d_in[18];
  const float* bg_diag   = (const float*)d_in[19];
  const float* Wg_proc   = (const float*)d_in[20];
  const float* bg_proc   = (const float*)d_in[21];

  const float scale = (float)(1.0 / sqrt(256.0 + 1e-7));

  char* ws = (char*)d_ws;
  const size_t sz_tf = (size_t)1280*256*4;
  const size_t szA_m = (size_t)32*960*256*2;
  const size_t szA_d = (size_t)32*1280*256*2;
  const size_t szA_p = (size_t)32*640*256*2;

  size_t off = 0;
  float* tf   = (float*)(ws + off); off += sz_tf;
  us* Am      = (us*)(ws + off);    off += szA_m;
  us* Ad      = (us*)(ws + off);    off += szA_d;
  us* Ap      = (us*)(ws + off);    off += szA_p;

  const size_t fused_need = off + 2*(szA_m + szA_d + szA_p);
  tf_kernel<<<1280, 256, 0, stream>>>(seq_time, W_sel, b_sel, W_time, b_time, tf);

  if (ws_size >= fused_need){
    us* Xm  = (us*)(ws + off); off += szA_m;
    us* XTm = (us*)(ws + off); off += szA_m;
    us* Xd  = (us*)(ws + off); off += szA_d;
    us* XTd = (us*)(ws + off); off += szA_d;
    us* Xp  = (us*)(ws + off); off += szA_p;
    us* XTp = (us*)(ws + off); off += szA_p;

    gate_fused<<<3840, 256, 0, stream>>>(
        med_codes, diag_codes, proc_codes, med_mask, diag_mask, proc_mask,
        emb_med, emb_diag, emb_proc, tf,
        Wg_med, bg_med, Wg_diag, bg_diag, Wg_proc, bg_proc,
        Xm, XTm, Xd, XTd, Xp, XTp, scale);

    visit_fused<<<736, 256, 0, stream>>>(Xm, XTm, Am, Xd, XTd, Ad, Xp, XTp, Ap, scale);
  } else {
    us* Xg  = (us*)(ws + off);
    us* XgT = (us*)(ws + off + szA_d);

    gate_kernel<24,960><<<1280, 256, 0, stream>>>(med_codes, med_mask, emb_med, tf, Wg_med, bg_med, Xg, XgT, scale);
    visit_kernel<960><<<dim3(8,32), 256, 0, stream>>>(Xg, XgT, Am, scale);

    gate_kernel<32,1280><<<1280, 256, 0, stream>>>(diag_codes, diag_mask, emb_diag, tf, Wg_diag, bg_diag, Xg, XgT, scale);
    visit_kernel<1280><<<dim3(10,32), 256, 0, stream>>>(Xg, XgT, Ad, scale);

    gate_kernel<16,640><<<1280, 256, 0, stream>>>(proc_codes, proc_mask, emb_proc, tf, Wg_proc, bg_proc, Xg, XgT, scale);
    visit_kernel<640><<<dim3(5,32), 256, 0, stream>>>(Xg, XgT, Ap, scale);
  }

  merge_kernel<<<1280, 512, 0, stream>>>(Am, Ad, Ap, tf, bias_med, input_len, (float*)d_out, scale);
}

// Round 7
// 438.068 us; speedup vs baseline: 1.6554x; 1.0219x over previous
//
#include <hip/hip_runtime.h>
#include <hip/hip_bf16.h>
#include <math.h>

// ---------------- types / helpers ----------------
typedef float f32x4 __attribute__((ext_vector_type(4)));
typedef short s16x8 __attribute__((ext_vector_type(8)));
typedef unsigned short us;

__device__ __forceinline__ float bf2f(us u){
  union { unsigned int i; float f; } v; v.i = ((unsigned int)u) << 16; return v.f;
}
__device__ __forceinline__ us f2bf(float f){
  union { float f; unsigned int i; } v; v.f = f;
  unsigned int r = v.i + 0x7FFFu + ((v.i >> 16) & 1u);
  return (us)(r >> 16);
}
__device__ __forceinline__ unsigned pack2bf(float a, float b){
  return (unsigned)f2bf(a) | ((unsigned)f2bf(b) << 16);
}
__device__ __forceinline__ float dot4(f32x4 a, f32x4 b){
  return a.x*b.x + a.y*b.y + a.z*b.z + a.w*b.w;
}
__device__ __forceinline__ f32x4 mfma16(s16x8 a, s16x8 b, f32x4 c){
  return __builtin_amdgcn_mfma_f32_16x16x32_bf16(a, b, c, 0, 0, 0);
}
// async global->LDS, 16B per lane; dst must be wave-uniform base (HW adds lane*16)
__device__ __forceinline__ void gld16(const us* src, us* dst){
  __builtin_amdgcn_global_load_lds(
      (const __attribute__((address_space(1))) unsigned int*)src,
      (__attribute__((address_space(3))) unsigned int*)dst, 16, 0, 0);
}

#define VM_WAIT16()  asm volatile("s_waitcnt vmcnt(16)" ::: "memory")
#define VM_WAIT0()   asm volatile("s_waitcnt vmcnt(0)" ::: "memory")
#define LGKM_WAIT0() asm volatile("s_waitcnt lgkmcnt(0)" ::: "memory")
#define BAR()        __builtin_amdgcn_s_barrier()
#define SCHED_FENCE() __builtin_amdgcn_sched_barrier(0)

// ---------------- 1) time_feature ----------------
__global__ __launch_bounds__(256) void tf_kernel(
    const float* __restrict__ seq, const float* __restrict__ Wsel,
    const float* __restrict__ bsel, const float* __restrict__ Wtime,
    const float* __restrict__ btime, float* __restrict__ tf)
{
  const int bt = blockIdx.x, tid = threadIdx.x;
  __shared__ float w1[64];
  float s = seq[bt];
  if (tid < 64){ float h = s*Wsel[tid] + bsel[tid]; w1[tid] = 1.0f - tanhf(h*h); }
  __syncthreads();
  const float* wrow = Wtime + (size_t)tid*64;
  float acc = btime[tid];
  #pragma unroll 8
  for (int j = 0; j < 64; ++j) acc += w1[j]*wrow[j];
  tf[(size_t)bt*256 + tid] = acc;
}

// ---------------- 2) embed + gate ----------------
struct GateLds {
  float E[32*260];
  float sc[64];
  float tfs[256];
  float gs[256];
};

template<int L, int N>
__device__ __forceinline__ void gate_body(GateLds& S,
    const int* __restrict__ codes, const float* __restrict__ mask,
    const float* __restrict__ emb, const float* __restrict__ tf,
    const float* __restrict__ Wg, const float* __restrict__ bg,
    us* __restrict__ Xg, us* __restrict__ XgT, float scale, int bt)
{
  const int b = bt/40, t = bt - (bt/40)*40;
  const int tid = threadIdx.x, lane = tid & 63, wid = tid >> 6;

  S.tfs[tid] = tf[(size_t)bt*256 + tid];
  #pragma unroll
  for (int l = 0; l < L; ++l){
    int code = codes[bt*L + l];
    float m = mask[bt*L + l];
    S.E[l*260 + tid] = emb[(size_t)code*256 + tid] * m;
  }
  __syncthreads();

  constexpr int RPW = (L + 3)/4;
  #pragma unroll
  for (int rr = 0; rr < RPW; ++rr){
    int l = wid*RPW + rr;
    if (l < L){
      f32x4 e4 = *(const f32x4*)&S.E[l*260 + lane*4];
      f32x4 t4 = *(const f32x4*)&S.tfs[lane*4];
      float p = dot4(e4, t4);
      #pragma unroll
      for (int m = 1; m < 64; m <<= 1) p += __shfl_xor(p, m, 64);
      if (lane == 0) S.sc[l] = p * scale;
    }
  }
  __syncthreads();
  if (wid == 0){
    float p = (lane < L) ? __expf(S.sc[lane]) : 0.f;
    float ss = p;
    #pragma unroll
    for (int m = 1; m < 64; m <<= 1) ss += __shfl_xor(ss, m, 64);
    if (lane < L) S.sc[lane] = p / ss;
  }
  __syncthreads();

  float g = 0.f;
  #pragma unroll
  for (int l = 0; l < L; ++l) g += S.sc[l]*S.E[l*260 + tid];
  S.gs[tid] = g;
  __syncthreads();

  const float* wrow = Wg + (size_t)tid*256;
  float a2 = bg[tid];
  #pragma unroll
  for (int e = 0; e < 256; e += 4){
    f32x4 w4 = *(const f32x4*)&wrow[e];
    f32x4 g4 = *(const f32x4*)&S.gs[e];
    a2 += dot4(w4, g4);
  }
  float g2 = 1.f/(1.f + __expf(-a2));

  us tbuf[L];
  #pragma unroll
  for (int l = 0; l < L; ++l){
    us h = f2bf(g2 * S.E[l*260 + tid]);
    Xg[((size_t)b*N + t*L + l)*256 + tid] = h;
    tbuf[l] = h;
  }
  size_t tb = ((size_t)b*256 + tid)*N + (size_t)t*L;
  #pragma unroll
  for (int l = 0; l < L; l += 8){
    uint4 v;
    v.x = (unsigned)tbuf[l+0] | ((unsigned)tbuf[l+1] << 16);
    v.y = (unsigned)tbuf[l+2] | ((unsigned)tbuf[l+3] << 16);
    v.z = (unsigned)tbuf[l+4] | ((unsigned)tbuf[l+5] << 16);
    v.w = (unsigned)tbuf[l+6] | ((unsigned)tbuf[l+7] << 16);
    *(uint4*)&XgT[tb + l] = v;
  }
}

template<int L, int N>
__global__ __launch_bounds__(256) void gate_kernel(
    const int* codes, const float* mask, const float* emb, const float* tf,
    const float* Wg, const float* bg, us* Xg, us* XgT, float scale)
{
  __shared__ GateLds S;
  gate_body<L,N>(S, codes, mask, emb, tf, Wg, bg, Xg, XgT, scale, blockIdx.x);
}

__global__ __launch_bounds__(256) void gate_fused(
    const int* mc, const int* dc, const int* pc,
    const float* mm, const float* dm, const float* pm,
    const float* em, const float* ed, const float* ep,
    const float* tf,
    const float* Wgm, const float* bgm, const float* Wgd, const float* bgd,
    const float* Wgp, const float* bgp,
    us* Xm, us* XTm, us* Xd, us* XTd, us* Xp, us* XTp, float scale)
{
  __shared__ GateLds S;
  int bid = blockIdx.x;
  if (bid < 1280)      gate_body<24,960 >(S, mc, mm, em, tf, Wgm, bgm, Xm, XTm, scale, bid);
  else if (bid < 2560) gate_body<32,1280>(S, dc, dm, ed, tf, Wgd, bgd, Xd, XTd, scale, bid-1280);
  else                 gate_body<16,640 >(S, pc, pm, ep, tf, Wgp, bgp, Xp, XTp, scale, bid-2560);
}

// ---------------- 3) visit self-attention ----------------
// KVBLK=64 staging (halved barrier/stage rate), KVBLK=32 compute (R4-small regs).
// 138 KB LDS -> forced 1 block/CU (L2 protection, round-5 lesson).
// Swapped QK^T (S^T = mfma(K,Q)) -> P packed u32 pairs, conflict-free
// stride-20 per-wave scratch (4 ds_write_b64 + 2 ds_read_b128 per half).
// V^T rows 128B with full (d&7)<<4 XOR swizzle -> 2-way (free).
// Row-sums via immediate ones-fragment MFMA (no LDS read, no shfl).
struct VisitLds {
  us ks[2][64*256];      // 2 x 32KB, K rows 512B, swizzled
  us vs[2][256*64];      // 2 x 32KB, V^T rows 128B, swizzled
  unsigned pw[4][32*20]; // per-wave P: 32 q-rows x 20 u32 (16 data + 4 pad)
};

__device__ __forceinline__ void stage_K(us* KS, const us* __restrict__ Xb,
                                        int k0, int tid)
{
  const int wid = tid >> 6;
  #pragma unroll
  for (int i = 0; i < 8; ++i){
    int c = tid + i*256;
    int row = c >> 5, ch = c & 31;
    gld16(Xb + (size_t)(k0 + row)*256 + (((ch*16) ^ ((row & 7) << 4)) >> 1),
          KS + (i*256 + wid*64)*8);
  }
}
__device__ __forceinline__ void stage_V(us* VS, const us* __restrict__ XTb,
                                        int k0, int N_, int tid)
{
  const int wid = tid >> 6;
  #pragma unroll
  for (int i = 0; i < 8; ++i){
    int c = tid + i*256;
    int d = c >> 3, chunk = c & 7;
    gld16(XTb + (size_t)d*N_ + k0 + ((chunk ^ (d & 7))*8),
          VS + (i*256 + wid*64)*8);
  }
}

template<int N>
__device__ __forceinline__ void visit_body(VisitLds& S,
    const us* __restrict__ Xb, const us* __restrict__ XTb,
    us* __restrict__ Outb, float scale, int q0)
{
  const int tid = threadIdx.x, lane = tid & 63, wid = tid >> 6;
  const int lc = lane & 15, lg = lane >> 4;

  // ---- direct-register Q loads (issue first; drain with first vmcnt) ----
  s16x8 qf[2][8];
  #pragma unroll
  for (int qg = 0; qg < 2; ++qg)
    #pragma unroll
    for (int kk = 0; kk < 8; ++kk){
      int gr = q0 + wid*32 + qg*16 + lc;
      gr = gr < N ? gr : N-1;
      qf[qg][kk] = *(const s16x8*)(Xb + (size_t)gr*256 + kk*32 + lg*8);
    }
  SCHED_FENCE();

  // prologue: 2-deep pair prefetch
  stage_K(S.ks[0], Xb, 0, tid);   stage_V(S.vs[0], XTb, 0, N, tid);
  stage_K(S.ks[1], Xb, 64, tid);  stage_V(S.vs[1], XTb, 64, N, tid);
  SCHED_FENCE();
  VM_WAIT16();     // Q(16) + pair0(16) landed; pair1's 16 may fly
  BAR();

  // immediate ones fragment for row sums
  s16x8 ONES;
  #pragma unroll
  for (int i = 0; i < 8; ++i) ONES[i] = (short)0x3F80;

  f32x4 o[2][16];
  #pragma unroll
  for (int qg = 0; qg < 2; ++qg)
    #pragma unroll
    for (int dcc = 0; dcc < 16; ++dcc) o[qg][dcc] = (f32x4){0.f,0.f,0.f,0.f};
  f32x4 ls[2] = {(f32x4){0.f,0.f,0.f,0.f}, (f32x4){0.f,0.f,0.f,0.f}};

  unsigned* pwq = S.pw[wid];
  const int np = N/64;

  for (int p = 0; p < np; ++p){
    const us* KS = S.ks[p & 1];
    const us* VS = S.vs[p & 1];

    #pragma unroll
    for (int h = 0; h < 2; ++h){
      // ---- S^T = K Q^T (A = K-rows, B = Q-rows; both contiguous-d frags) ----
      f32x4 st[2][2];
      #pragma unroll
      for (int kc = 0; kc < 2; ++kc)
        #pragma unroll
        for (int qg = 0; qg < 2; ++qg) st[kc][qg] = (f32x4){0.f,0.f,0.f,0.f};

      __builtin_amdgcn_s_setprio(1);
      #pragma unroll
      for (int kk = 0; kk < 8; ++kk){
        #pragma unroll
        for (int kc = 0; kc < 2; ++kc){
          int row = h*32 + kc*16 + lc;
          int off = kk*64 + lg*16;
          s16x8 kb = *(const s16x8*)((const char*)KS + row*512 + (off ^ ((row & 7) << 4)));
          st[kc][0] = mfma16(kb, qf[0][kk], st[kc][0]);
          st[kc][1] = mfma16(kb, qf[1][kk], st[kc][1]);
        }
      }
      __builtin_amdgcn_s_setprio(0);

      // ---- P = exp(scale*S): lane holds P[q=qg*16+lc][key=kc*16+lg*4+r] ----
      // pack key-pairs into u32, store at [q][kc*8 + lg*2 + pr] (stride 20)
      #pragma unroll
      for (int qg = 0; qg < 2; ++qg){
        #pragma unroll
        for (int kc = 0; kc < 2; ++kc){
          float e0 = __expf(st[kc][qg][0] * scale);
          float e1 = __expf(st[kc][qg][1] * scale);
          float e2 = __expf(st[kc][qg][2] * scale);
          float e3 = __expf(st[kc][qg][3] * scale);
          uint2 u; u.x = pack2bf(e0, e1); u.y = pack2bf(e2, e3);
          *(uint2*)&pwq[(qg*16 + lc)*20 + kc*8 + lg*2] = u;
        }
      }
      s16x8 pa[2];
      #pragma unroll
      for (int qg = 0; qg < 2; ++qg)
        pa[qg] = *(const s16x8*)&pwq[(qg*16 + lc)*20 + lg*4];

      // ---- O += P V ; row-sums via immediate ones fragment ----
      __builtin_amdgcn_s_setprio(1);
      #pragma unroll
      for (int dcc = 0; dcc < 16; ++dcc){
        int d = dcc*16 + lc;
        s16x8 vf = *(const s16x8*)((const char*)VS + ((d*128 + h*64 + lg*16) ^ ((d & 7) << 4)));
        o[0][dcc] = mfma16(pa[0], vf, o[0][dcc]);
        o[1][dcc] = mfma16(pa[1], vf, o[1][dcc]);
      }
      ls[0] = mfma16(pa[0], ONES, ls[0]);
      ls[1] = mfma16(pa[1], ONES, ls[1]);
      __builtin_amdgcn_s_setprio(0);
    }

    if (p + 1 == np) break;
    SCHED_FENCE();
    LGKM_WAIT0();            // this wave's LDS reads of bufs[p&1] retired
    BAR();                   // all waves done with bufs[p&1]
    if (p + 2 < np){
      stage_K(S.ks[p & 1], Xb, (p+2)*64, tid);
      stage_V(S.vs[p & 1], XTb, (p+2)*64, N, tid);
      VM_WAIT16();           // pair p+1 fully landed; p+2's 16 may fly
    } else {
      VM_WAIT0();            // drain: guarantee p+1
    }
    BAR();                   // pair p+1 visible to all waves
    SCHED_FENCE();
  }

  // epilogue: D rows = q (lg*4+r); ls holds row-sum in every lane (ones cols)
  #pragma unroll
  for (int qg = 0; qg < 2; ++qg){
    #pragma unroll
    for (int r = 0; r < 4; ++r){
      float inv = 1.f / ls[qg][r];
      int grow = q0 + wid*32 + qg*16 + lg*4 + r;
      if (grow < N){
        #pragma unroll
        for (int dcc = 0; dcc < 16; ++dcc){
          Outb[(size_t)grow*256 + dcc*16 + lc] = f2bf(o[qg][dcc][r] * inv);
        }
      }
    }
  }
}

template<int N>
__global__ __launch_bounds__(256, 2) void visit_kernel(
    const us* Xg, const us* XgT, us* Out, float scale)
{
  __shared__ VisitLds S;
  const int b = blockIdx.y;
  visit_body<N>(S, Xg + (size_t)b*N*256, XgT + (size_t)b*256*N,
                Out + (size_t)b*N*256, scale, blockIdx.x*128);
}

__global__ __launch_bounds__(256, 2) void visit_fused(
    const us* Xm, const us* XTm, us* Am,
    const us* Xd, const us* XTd, us* Ad,
    const us* Xp, const us* XTp, us* Ap, float scale)
{
  __shared__ VisitLds S;
  // XCD-locality remap (736 = 8*92): contiguous logical chunk per XCD.
  // Longest-first: diag (20 pair-iters), med (15), proc (10).
  int p = blockIdx.x;
  int l = (p & 7)*92 + (p >> 3);
  if (l < 320){
    int b = l/10, q0 = (l - (l/10)*10)*128;
    visit_body<1280>(S, Xd + (size_t)b*1280*256, XTd + (size_t)b*256*1280,
                     Ad + (size_t)b*1280*256, scale, q0);
  } else if (l < 576){
    int r = l - 320, b = r >> 3, q0 = (r & 7)*128;
    visit_body<960>(S, Xm + (size_t)b*960*256, XTm + (size_t)b*256*960,
                    Am + (size_t)b*960*256, scale, q0);
  } else {
    int r = l - 576, b = r/5, q0 = (r - (r/5)*5)*128;
    visit_body<640>(S, Xp + (size_t)b*640*256, XTp + (size_t)b*256*640,
                    Ap + (size_t)b*640*256, scale, q0);
  }
}

// ---------------- 4) merge attention + med_att, fused per (b,t), all-MFMA GEMMs ----------------
__global__ __launch_bounds__(512, 4) void merge_kernel(
    const us* __restrict__ Amed, const us* __restrict__ Adiag,
    const us* __restrict__ Aproc, const float* __restrict__ tf,
    const float* __restrict__ bias, const int* __restrict__ ilen,
    float* __restrict__ out, float scale)
{
  __shared__ alignas(16) us A[80*256];    // 40960 B
  __shared__ alignas(16) us SrB[80*96];   // 15360 B
  us* Mb  = A;                             // phases 1-2 (dead after 2)
  us* Pb  = A;                             // phases 3+ (7680 shorts)
  us* W1B = A + 7680;                      // 3072 shorts
  float* wj  = (float*)(A + 10752);        // 73 floats
  float* uk  = (float*)(A + 10912);        // 73 floats
  float* S2f = (float*)SrB;                // aliases SrB after phase 4

  const int bt = blockIdx.x, b = bt/40, t = bt - (bt/40)*40;
  const int tid = threadIdx.x, lane = tid & 63, wid = tid >> 6;
  const int lc = lane & 15, lg = lane >> 4;

  for (int c = tid; c < 72*32; c += 512){
    int row = c >> 5, ch = c & 31;
    const us* src;
    if (row < 24)      src = Amed  + ((size_t)b*960  + t*24 + row)*256      + ch*8;
    else if (row < 56) src = Adiag + ((size_t)b*1280 + t*32 + (row-24))*256 + ch*8;
    else               src = Aproc + ((size_t)b*640  + t*16 + (row-56))*256 + ch*8;
    uint4 v = *(const uint4*)src;
    *(uint4*)((char*)Mb + row*512 + ((ch*16) ^ ((row & 7) << 4))) = v;
  }
  if (tid < 256) Mb[72*256 + tid] = f2bf(tf[(size_t)bt*256 + tid]);
  for (int c = tid; c < 7*32; c += 512){
    int row = 73 + (c >> 5), ch = c & 31;
    *(uint4*)((char*)Mb + row*512 + ch*16) = (uint4){0,0,0,0};
  }
  __syncthreads();

  for (int tt = wid; tt < 25; tt += 8){
    int ti = tt/5, tj = tt - (tt/5)*5;
    f32x4 s = (f32x4){0.f,0.f,0.f,0.f};
    #pragma unroll
    for (int kk = 0; kk < 8; ++kk){
      int ra = ti*16 + lc, rb = tj*16 + lc;
      int off = kk*64 + lg*16;
      s16x8 a  = *(const s16x8*)((const char*)Mb + ra*512 + (off ^ ((ra & 7) << 4)));
      s16x8 bb = *(const s16x8*)((const char*)Mb + rb*512 + (off ^ ((rb & 7) << 4)));
      s = mfma16(a, bb, s);
    }
    #pragma unroll
    for (int r = 0; r < 4; ++r)
      SrB[(ti*16 + lg*4 + r)*96 + tj*16 + lc] = f2bf(s[r]);
  }
  __syncthreads();   // Mb dead from here; A reused as Pb/W1B/wj/uk

  for (int c = tid; c < 80*16; c += 512){
    int r = c >> 4;
    SrB[r*96 + 80 + (c & 15)] = 0;
  }
  for (int r = wid; r < 73; r += 8){
    float e0 = __expf(scale * bf2f(SrB[r*96 + lane]));
    float e1 = (lane < 9) ? __expf(scale * bf2f(SrB[r*96 + 64 + lane])) : 0.f;
    float ss = e0 + e1;
    #pragma unroll
    for (int m = 1; m < 64; m <<= 1) ss += __shfl_xor(ss, m, 64);
    float inv = 1.f/ss;
    Pb[r*96 + lane] = f2bf(e0 * inv);
    if (lane < 32) Pb[r*96 + 64 + lane] = (lane < 9) ? f2bf(e1*inv) : (us)0;
  }
  for (int c = tid; c < 7*96; c += 512){
    Pb[73*96 + c] = 0;
  }
  __syncthreads();

  for (int tt = wid; tt < 10; tt += 8){
    int ri = tt/5, cj = tt - (tt/5)*5;
    f32x4 s = (f32x4){0.f,0.f,0.f,0.f};
    #pragma unroll
    for (int kk = 0; kk < 3; ++kk){
      s16x8 a  = *(const s16x8*)(Pb  + (ri*16 + lc)*96 + kk*32 + lg*8);
      s16x8 bb = *(const s16x8*)(SrB + (cj*16 + lc)*96 + kk*32 + lg*8);
      s = mfma16(a, bb, s);
    }
    #pragma unroll
    for (int r = 0; r < 4; ++r)
      W1B[(ri*16 + lg*4 + r)*96 + cj*16 + lc] = f2bf(s[r]);
  }
  if (tid < 512){
    W1B[(tid >> 4)*96 + 80 + (tid & 15)] = 0;
  }
  __syncthreads();

  for (int tt = wid; tt < 10; tt += 8){
    int ri = tt/5, cj = tt - (tt/5)*5;
    f32x4 s = (f32x4){0.f,0.f,0.f,0.f};
    #pragma unroll
    for (int kk = 0; kk < 3; ++kk){
      s16x8 a  = *(const s16x8*)(W1B + (ri*16 + lc)*96 + kk*32 + lg*8);
      s16x8 bb = *(const s16x8*)(Pb  + (cj*16 + lc)*96 + kk*32 + lg*8);
      s = mfma16(a, bb, s);
    }
    #pragma unroll
    for (int r = 0; r < 4; ++r)
      S2f[(ri*16 + lg*4 + r)*84 + cj*16 + lc] = s[r];
  }
  __syncthreads();

  for (int r = wid; r < 24; r += 8){
    float e0 = __expf(S2f[r*84 + lane]);
    float e1 = (lane < 9) ? __expf(S2f[r*84 + 64 + lane]) : 0.f;
    float ss = e0 + e1;
    #pragma unroll
    for (int m = 1; m < 64; m <<= 1) ss += __shfl_xor(ss, m, 64);
    float inv = 1.f/ss;
    S2f[r*84 + lane] = e0*inv;
    if (lane < 12) S2f[r*84 + 64 + lane] = (lane < 9) ? e1*inv : 0.f;
  }
  __syncthreads();

  if (tid < 73){
    float a = 0.f;
    #pragma unroll
    for (int i = 0; i < 24; ++i) a += S2f[i*84 + tid];
    wj[tid] = a;
  }
  __syncthreads();
  if (tid < 73){
    float a = 0.f;
    for (int j = 0; j < 73; ++j) a += wj[j] * bf2f(Pb[j*96 + tid]);
    uk[tid] = a;
  }
  __syncthreads();

  if (tid < 256){
    float acc = bias[tid];
    if (t < ilen[b]){
      float ex = (float)(2*(tid>>1)) * (1.0f/256.0f);
      float dv = powf(10000.f, ex);
      float ang = (float)t / dv;
      acc += (tid & 1) ? cosf(ang) : sinf(ang);
    }
    const us* Am_ = Amed  + ((size_t)b*960  + t*24)*256 + tid;
    #pragma unroll 4
    for (int k = 0; k < 24; ++k) acc += uk[k]      * bf2f(Am_[k*256]);
    const us* Ad_ = Adiag + ((size_t)b*1280 + t*32)*256 + tid;
    #pragma unroll 4
    for (int k = 0; k < 32; ++k) acc += uk[24 + k] * bf2f(Ad_[k*256]);
    const us* Ap_ = Aproc + ((size_t)b*640  + t*16)*256 + tid;
    #pragma unroll 4
    for (int k = 0; k < 16; ++k) acc += uk[56 + k] * bf2f(Ap_[k*256]);
    acc += uk[72] * tf[(size_t)bt*256 + tid];
    out[(size_t)bt*256 + tid] = acc;
  }
}

// ---------------- launch ----------------
extern "C" void kernel_launch(void* const* d_in, const int* in_sizes, int n_in,
                              void* d_out, int out_size, void* d_ws, size_t ws_size,
                              hipStream_t stream)
{
  (void)in_sizes; (void)n_in; (void)out_size;

  const int*   med_codes = (const int*)  d_in[0];
  const int*   diag_codes= (const int*)  d_in[1];
  const int*   proc_codes= (const int*)  d_in[2];
  const float* med_mask  = (const float*)d_in[3];
  const float* diag_mask = (const float*)d_in[4];
  const float* proc_mask = (const float*)d_in[5];
  const float* seq_time  = (const float*)d_in[6];
  const int*   input_len = (const int*)  d_in[7];
  const float* emb_med   = (const float*)d_in[8];
  const float* emb_diag  = (const float*)d_in[9];
  const float* emb_proc  = (const float*)d_in[10];
  const float* bias_med  = (const float*)d_in[11];
  const float* W_sel     = (const float*)d_in[12];
  const float* b_sel     = (const float*)d_in[13];
  const float* W_time    = (const float*)d_in[14];
  const float* b_time    = (const float*)d_in[15];
  const float* Wg_med    = (const float*)d_in[16];
  const float* bg_med    = (const float*)d_in[17];
  const float* Wg_diag   = (const float*)d_in[18];
  const float* bg_diag   = (const float*)d_in[19];
  const float* Wg_proc   = (const float*)d_in[20];
  const float* bg_proc   = (const float*)d_in[21];

  const float scale = (float)(1.0 / sqrt(256.0 + 1e-7));

  char* ws = (char*)d_ws;
  const size_t sz_tf = (size_t)1280*256*4;
  const size_t szA_m = (size_t)32*960*256*2;
  const size_t szA_d = (size_t)32*1280*256*2;
  const size_t szA_p = (size_t)32*640*256*2;

  size_t off = 0;
  float* tf   = (float*)(ws + off); off += sz_tf;
  us* Am      = (us*)(ws + off);    off += szA_m;
  us* Ad      = (us*)(ws + off);    off += szA_d;
  us* Ap      = (us*)(ws + off);    off += szA_p;

  const size_t fused_need = off + 2*(szA_m + szA_d + szA_p);
  tf_kernel<<<1280, 256, 0, stream>>>(seq_time, W_sel, b_sel, W_time, b_time, tf);

  if (ws_size >= fused_need){
    us* Xm  = (us*)(ws + off); off += szA_m;
    us* XTm = (us*)(ws + off); off += szA_m;
    us* Xd  = (us*)(ws + off); off += szA_d;
    us* XTd = (us*)(ws + off); off += szA_d;
    us* Xp  = (us*)(ws + off); off += szA_p;
    us* XTp = (us*)(ws + off); off += szA_p;

    gate_fused<<<3840, 256, 0, stream>>>(
        med_codes, diag_codes, proc_codes, med_mask, diag_mask, proc_mask,
        emb_med, emb_diag, emb_proc, tf,
        Wg_med, bg_med, Wg_diag, bg_diag, Wg_proc, bg_proc,
        Xm, XTm, Xd, XTd, Xp, XTp, scale);

    visit_fused<<<736, 256, 0, stream>>>(Xm, XTm, Am, Xd, XTd, Ad, Xp, XTp, Ap, scale);
  } else {
    us* Xg  = (us*)(ws + off);
    us* XgT = (us*)(ws + off + szA_d);

    gate_kernel<24,960><<<1280, 256, 0, stream>>>(med_codes, med_mask, emb_med, tf, Wg_med, bg_med, Xg, XgT, scale);
    visit_kernel<960><<<dim3(8,32), 256, 0, stream>>>(Xg, XgT, Am, scale);

    gate_kernel<32,1280><<<1280, 256, 0, stream>>>(diag_codes, diag_mask, emb_diag, tf, Wg_diag, bg_diag, Xg, XgT, scale);
    visit_kernel<1280><<<dim3(10,32), 256, 0, stream>>>(Xg, XgT, Ad, scale);

    gate_kernel<16,640><<<1280, 256, 0, stream>>>(proc_codes, proc_mask, emb_proc, tf, Wg_proc, bg_proc, Xg, XgT, scale);
    visit_kernel<640><<<dim3(5,32), 256, 0, stream>>>(Xg, XgT, Ap, scale);
  }

  merge_kernel<<<1280, 512, 0, stream>>>(Am, Ad, Ap, tf, bias_med, input_len, (float*)d_out, scale);
}